// Round 19
// baseline (110.362 us; speedup 1.0000x reference)
//
#include <hip/hip_runtime.h>

#define DIM 64
#define NBUCK 256
#define BSHIFT 9
#define BCAP 12288
#define CHUNK 4096

typedef __attribute__((ext_vector_type(4))) float f32x4;
typedef __attribute__((ext_vector_type(2))) float f32x2v;
typedef __attribute__((ext_vector_type(8))) short short8;

#define MFMA16(a, b, c) __builtin_amdgcn_mfma_f32_16x16x32_bf16(a, b, c, 0, 0, 0)

template <int CTRL>
__device__ __forceinline__ float qperm(float v) {
    return __int_as_float(__builtin_amdgcn_update_dpp(
        0, __float_as_int(v), CTRL, 0xF, 0xF, true));
}

// split fp32 -> bf16 hi + bf16 lo (truncation; dropped term ~2^-16 rel)
__device__ __forceinline__ void cvt8(const float* f, short8& hi, short8& lo) {
#pragma unroll
    for (int e = 0; e < 8; ++e) {
        const unsigned u = __float_as_uint(f[e]);
        hi[e] = (short)(u >> 16);
        const float hf = __uint_as_float(u & 0xFFFF0000u);
        lo[e] = (short)(__float_as_uint(f[e] - hf) >> 16);
    }
}

__device__ __forceinline__ unsigned short bf16rne(float f) {
    const unsigned u = __float_as_uint(f);
    return (unsigned short)((u + 0x7FFFu + ((u >> 16) & 1u)) >> 16);
}

// Weight fragments; zero bcursor; edata sentinels; offsets[N]=E.
__global__ __launch_bounds__(256) void prep_kernel(
    const float* __restrict__ Wl, const float* __restrict__ Wh,
    const float* __restrict__ W1, const float* __restrict__ W2,
    short8* __restrict__ wf, int* __restrict__ bcursor,
    int* __restrict__ edata, int* __restrict__ offsets, int N, int E)
{
    const int tid = threadIdx.x;
    bcursor[tid] = 0;
    edata[E + tid] = 0;
    edata[E + 256 + tid] = 0;
    if (tid == 0) offsets[N] = E;
    const int m = tid >> 6, l = tid & 63;
    const float* W = (m == 0) ? Wl : (m == 1) ? Wh : (m == 2) ? W1 : W2;
    const int o = l & 15;
    const int kg = (l >> 4) * 8;
#pragma unroll
    for (int t = 0; t < 4; ++t)
#pragma unroll
        for (int s = 0; s < 2; ++s) {
            float f[8];
#pragma unroll
            for (int e = 0; e < 8; ++e)
                f[e] = W[(o + 16 * t) * DIM + 32 * s + kg + e];
            short8 hi, lo;
            cvt8(f, hi, lo);
            const int base = (((m * 4 + t) * 2 + s) * 2);
            wf[(base + 0) * 64 + l] = hi;
            wf[(base + 1) * 64 + l] = lo;
        }
}

__device__ __forceinline__ int wave_incl_scan(int v, int lane) {
#pragma unroll
    for (int off = 1; off < 64; off <<= 1) {
        int t = __shfl_up(v, (unsigned)off, 64);
        if (lane >= off) v += t;
    }
    return v;
}

// Fused: odd blocks = h-projection GEMM (MFMA); even blocks = edge binning.
// Bin counting-sorts its chunk IN LDS, then streams records out coalesced.
__global__ __launch_bounds__(256, 3) void gemmbin_kernel(
    const float* __restrict__ x, const short8* __restrict__ wf,
    const float* __restrict__ bias, float* __restrict__ h,
    unsigned short* __restrict__ hb, int N,
    const int* __restrict__ ei, const int* __restrict__ sgn,
    int* __restrict__ bcursor, int* __restrict__ records,
    unsigned int* __restrict__ cnts, int E, int NB)
{
    if (blockIdx.x & 1) {
        // ---------------- GEMM path ----------------
        const int l = threadIdx.x & 63;
        const int gw = (blockIdx.x >> 1) * 4 + (threadIdx.x >> 6);
        const int nw = NB * 4;
        const int nstrips = (N + 15) >> 4;
        const int lr = l & 15, lk = (l >> 4) * 8, lrow4 = (l >> 4) * 4;

        short8 wh_[4][2], wl_[4][2];
#pragma unroll
        for (int t = 0; t < 4; ++t)
#pragma unroll
            for (int s = 0; s < 2; ++s) {
                wh_[t][s] = wf[(((0 * 4 + t) * 2 + s) * 2 + 0) * 64 + l];
                wl_[t][s] = wf[(((0 * 4 + t) * 2 + s) * 2 + 1) * 64 + l];
            }
        float b4[4];
#pragma unroll
        for (int t = 0; t < 4; ++t) b4[t] = bias[lr + 16 * t];

        for (int strip = gw; strip < nstrips; strip += nw) {
            const int rbase = strip * 16;
            const int arow = min(rbase + lr, N - 1);
            short8 ah[2], al[2];
#pragma unroll
            for (int s = 0; s < 2; ++s) {
                const float4 p0 = *reinterpret_cast<const float4*>(x + (size_t)arow * DIM + 32 * s + lk);
                const float4 p1 = *reinterpret_cast<const float4*>(x + (size_t)arow * DIM + 32 * s + lk + 4);
                float f[8] = {p0.x, p0.y, p0.z, p0.w, p1.x, p1.y, p1.z, p1.w};
                cvt8(f, ah[s], al[s]);
            }
            f32x4 acc[4];
#pragma unroll
            for (int t = 0; t < 4; ++t) acc[t] = (f32x4){b4[t], b4[t], b4[t], b4[t]};
#pragma unroll
            for (int s = 0; s < 2; ++s) {
#pragma unroll
                for (int t = 0; t < 4; ++t) acc[t] = MFMA16(ah[s], wh_[t][s], acc[t]);
#pragma unroll
                for (int t = 0; t < 4; ++t) acc[t] = MFMA16(ah[s], wl_[t][s], acc[t]);
#pragma unroll
                for (int t = 0; t < 4; ++t) acc[t] = MFMA16(al[s], wh_[t][s], acc[t]);
            }
#pragma unroll
            for (int t = 0; t < 4; ++t)
#pragma unroll
                for (int rg = 0; rg < 4; ++rg) {
                    const int row = rbase + lrow4 + rg;
                    if (row < N) {
                        h[(size_t)row * DIM + lr + 16 * t] = acc[t][rg];
                        hb[(size_t)row * DIM + lr + 16 * t] = bf16rne(acc[t][rg]);
                    }
                }
        }
    } else {
        // ---------------- bin path: in-LDS counting sort ----------------
        const int tid = threadIdx.x;
        const int lane = tid & 63, w = tid >> 6;
        const int blk = blockIdx.x >> 1;
        const int base = blk * CHUNK;
        __shared__ int lcnt[NBUCK];
        __shared__ int lpre[NBUCK];
        __shared__ int wtot_s[4];
        __shared__ int stag[CHUNK];
        lcnt[tid] = 0;
        __syncthreads();
        const int lim = min(CHUNK, E - base);
        if (lim == CHUNK && (E & 3) == 0) {
            int r[16];
#pragma unroll
            for (int j = 0; j < 4; ++j) {
                const int4 a = *(reinterpret_cast<const int4*>(ei + base) + tid * 4 + j);
                r[4*j+0]=a.x; r[4*j+1]=a.y; r[4*j+2]=a.z; r[4*j+3]=a.w;
            }
#pragma unroll
            for (int i = 0; i < 16; ++i) atomicAdd(&lcnt[r[i] >> BSHIFT], 1);
            __syncthreads();
            {
                const int v = lcnt[tid];
                const int inc = wave_incl_scan(v, lane);
                if (lane == 63) wtot_s[w] = inc;
                __syncthreads();
                int add = 0;
#pragma unroll
                for (int i = 0; i < 4; ++i)
                    if (i < w) add += wtot_s[i];
                const int pre = add + inc - v;
                lpre[tid] = pre;
                cnts[blk * NBUCK + tid] = (unsigned)pre | ((unsigned)v << 16);
                if (v) atomicAdd(&bcursor[tid], v);
            }
            __syncthreads();
            lcnt[tid] = 0;
            __syncthreads();
            int cc[16], ss[16];
#pragma unroll
            for (int j = 0; j < 4; ++j) {
                const int4 a = *(reinterpret_cast<const int4*>(ei + E + base) + tid * 4 + j);
                cc[4*j+0]=a.x; cc[4*j+1]=a.y; cc[4*j+2]=a.z; cc[4*j+3]=a.w;
                const int4 s2 = *(reinterpret_cast<const int4*>(sgn + base) + tid * 4 + j);
                ss[4*j+0]=s2.x; ss[4*j+1]=s2.y; ss[4*j+2]=s2.z; ss[4*j+3]=s2.w;
            }
#pragma unroll
            for (int i = 0; i < 16; ++i) {
                const int bkt = r[i] >> BSHIFT;
                const int idx = lpre[bkt] + atomicAdd(&lcnt[bkt], 1);
                stag[idx] = cc[i] | (ss[i] << 17) | ((r[i] & 511) << 18);
            }
            __syncthreads();
            for (int i = tid * 4; i < CHUNK; i += 1024)
                *reinterpret_cast<int4*>(records + base + i) =
                    *reinterpret_cast<const int4*>(stag + i);
        } else {
            for (int k = tid; k < lim; k += 256)
                atomicAdd(&lcnt[ei[base + k] >> BSHIFT], 1);
            __syncthreads();
            {
                const int v = lcnt[tid];
                const int inc = wave_incl_scan(v, lane);
                if (lane == 63) wtot_s[w] = inc;
                __syncthreads();
                int add = 0;
#pragma unroll
                for (int i = 0; i < 4; ++i)
                    if (i < w) add += wtot_s[i];
                const int pre = add + inc - v;
                lpre[tid] = pre;
                cnts[blk * NBUCK + tid] = (unsigned)pre | ((unsigned)v << 16);
                if (v) atomicAdd(&bcursor[tid], v);
            }
            __syncthreads();
            lcnt[tid] = 0;
            __syncthreads();
            for (int k = tid; k < lim; k += 256) {
                const int e = base + k;
                const int rr = ei[e];
                const int cc2 = ei[E + e];
                const int s = sgn[e];
                const int b = rr >> BSHIFT;
                const int idx = lpre[b] + atomicAdd(&lcnt[b], 1);
                stag[idx] = cc2 | (s << 17) | ((rr & 511) << 18);
            }
            __syncthreads();
            for (int i = tid; i < lim; i += 256)
                records[base + i] = stag[i];
        }
    }
}

// One WG per bucket: gather dense per-block runs -> stag, node-sort, emit CSR.
__global__ __launch_bounds__(256) void build_kernel(
    const int* __restrict__ records, const unsigned int* __restrict__ cnts,
    const int* __restrict__ bcursor,
    int* __restrict__ offsets, int* __restrict__ edata, int N, int NB)
{
    const int b = blockIdx.x;
    const int tid = threadIdx.x, lane = tid & 63, w = tid >> 6;
    const int nbase = b << BSHIFT;
    const int nn = min(512, N - nbase);
    if (nn <= 0) return;

    __shared__ int stag[BCAP];
    __shared__ int ncnt[512];
    __shared__ int wtot[8];
    __shared__ int csrb_l[NBUCK];
    __shared__ int blkoff[512];

    {
        const int bv = min(bcursor[tid], BCAP);
        const int inc = wave_incl_scan(bv, lane);
        if (lane == 63) wtot[w] = inc;
        __syncthreads();
        int add = 0;
#pragma unroll
        for (int i = 0; i < 4; ++i)
            if (i < w) add += wtot[i];
        csrb_l[tid] = add + inc - bv;
        __syncthreads();
    }
    const int base_csr = csrb_l[b];
    const int cntb = min(bcursor[b], BCAP);

    const unsigned pc0 = (tid < NB) ? cnts[tid * NBUCK + b] : 0u;
    const unsigned pc1 = (256 + tid < NB) ? cnts[(256 + tid) * NBUCK + b] : 0u;
    const int c0 = (int)(pc0 >> 16), c1 = (int)(pc1 >> 16);
    __syncthreads();
    {
        const int i0 = wave_incl_scan(c0, lane);
        if (lane == 63) wtot[w] = i0;
        const int i1 = wave_incl_scan(c1, lane);
        if (lane == 63) wtot[4 + w] = i1;
        __syncthreads();
        int a0 = 0, a1 = 0;
#pragma unroll
        for (int i = 0; i < 4; ++i) {
            if (i < w) { a0 += wtot[i]; a1 += wtot[4 + i]; }
        }
        const int half = wtot[0] + wtot[1] + wtot[2] + wtot[3];
        blkoff[tid] = a0 + i0 - c0;
        blkoff[256 + tid] = half + a1 + i1 - c1;
    }
    __syncthreads();

    if (tid < NB) {
        const int* src = records + tid * CHUNK + (int)(pc0 & 0xFFFFu);
        const int dst = blkoff[tid];
        for (int i = 0; i < c0; ++i) stag[dst + i] = src[i];
    }
    if (256 + tid < NB) {
        const int* src = records + (256 + tid) * CHUNK + (int)(pc1 & 0xFFFFu);
        const int dst = blkoff[256 + tid];
        for (int i = 0; i < c1; ++i) stag[dst + i] = src[i];
    }
    __syncthreads();

    ncnt[tid] = 0; ncnt[256 + tid] = 0;
    __syncthreads();
    for (int i = tid; i < cntb; i += 256)
        atomicAdd(&ncnt[stag[i] >> 18], 1);
    __syncthreads();
    const int v0 = ncnt[tid], v1 = ncnt[256 + tid];
    const int i0 = wave_incl_scan(v0, lane);
    if (lane == 63) wtot[w] = i0;
    const int i1 = wave_incl_scan(v1, lane);
    if (lane == 63) wtot[4 + w] = i1;
    __syncthreads();
    int a0 = 0, a1 = 0;
#pragma unroll
    for (int i = 0; i < 4; ++i) {
        if (i < w) { a0 += wtot[i]; a1 += wtot[4 + i]; }
    }
    const int half = wtot[0] + wtot[1] + wtot[2] + wtot[3];
    const int e0 = a0 + i0 - v0;
    const int e1 = half + a1 + i1 - v1;
    if (tid < nn)       offsets[nbase + tid]       = base_csr + e0;
    if (256 + tid < nn) offsets[nbase + 256 + tid] = base_csr + e1;
    __syncthreads();
    ncnt[tid] = e0; ncnt[256 + tid] = e1;
    __syncthreads();
    for (int i = tid; i < cntb; i += 256) {
        const int rcd = stag[i];
        const int p = atomicAdd(&ncnt[rcd >> 18], 1);
        edata[base_csr + p] = (rcd & 0x1FFFF) | (((rcd >> 17) & 1) << 20);
    }
}

// Fused attention + tail. Block = one 16-row strip (16 nodes, 4 waves).
// Degree-balanced wave assignment: 16 nodes rank-sorted by degree; wave w
// takes sorted ranks 4w..4w+3 -> maxdeg waste ~27% -> ~8%.
__global__ __launch_bounds__(256) void attntail_kernel(
    const float* __restrict__ h, const unsigned short* __restrict__ hb,
    const int* __restrict__ offsets, const int* __restrict__ edata,
    const float* __restrict__ sign_tab, const short8* __restrict__ wf,
    const float* __restrict__ bh, const float* __restrict__ b1,
    const float* __restrict__ b2, const float* __restrict__ eps,
    float* __restrict__ out, int N)
{
    __shared__ float bufA[16 * 68];
    __shared__ float bufB[16 * 68];
    __shared__ int degs[16];
    __shared__ int perm[16];

    const int lane = threadIdx.x & 63;
    const int w    = threadIdx.x >> 6;      // wave id = column tile
    const int gl   = lane & 15;
    const int g    = lane >> 4;
    const int rbase = blockIdx.x * 16;

    // rank-sort the strip's 16 nodes by degree
    if (threadIdx.x < 16) {
        const int nd = rbase + threadIdx.x;
        degs[threadIdx.x] = (nd < N) ? (offsets[nd + 1] - offsets[nd]) : 0;
    }
    __syncthreads();
    if (threadIdx.x < 16) {
        const int d = degs[threadIdx.x];
        int rank = 0;
#pragma unroll
        for (int j = 0; j < 16; ++j) {
            const int dj = degs[j];
            rank += (dj < d) || (dj == d && j < threadIdx.x);
        }
        perm[rank] = threadIdx.x;
    }
    __syncthreads();

    const int sub  = perm[(w << 2) + g];     // strip-row this group handles
    const int node = rbase + sub;
    const bool alive = node < N;
    const int nidx = alive ? node : 0;

    // ---------------- attention phase ----------------
    const int beg = offsets[nidx];
    const int deg = alive ? (offsets[nidx + 1] - beg) : 0;

    const float4 hi = *reinterpret_cast<const float4*>(h + ((unsigned)nidx << 6) + (gl << 2));
    const float L2E = 1.44269504f;
    const float4 hiL = make_float4(hi.x * L2E, hi.y * L2E, hi.z * L2E, hi.w * L2E);
    const float4 s0 = *reinterpret_cast<const float4*>(sign_tab + ((gl & 3) << 2));
    const float4 s1 = *reinterpret_cast<const float4*>(sign_tab + 16 + ((gl & 3) << 2));
    const f32x2v hs0a = {hiL.x * s0.x, hiL.y * s0.y};
    const f32x2v hs0b = {hiL.z * s0.z, hiL.w * s0.w};
    const f32x2v hs1a = {hiL.x * s1.x, hiL.y * s1.y};
    const f32x2v hs1b = {hiL.z * s1.z, hiL.w * s1.w};

    int maxdeg = max(deg, __shfl_xor(deg, 16, 64));
    maxdeg = max(maxdeg, __shfl_xor(maxdeg, 32, 64));

    float den = 0.f;
    f32x2v ma = {0.f, 0.f}, mb = {0.f, 0.f};
    const unsigned glb = (unsigned)(gl << 3);

    for (int e = 0; e < maxdeg; e += 8) {
        int pk[8];
#pragma unroll
        for (int u = 0; u < 8; ++u)
            pk[u] = edata[(unsigned)(beg + e + u)];
        uint2 v[8];
#pragma unroll
        for (int u = 0; u < 8; ++u) {
            unsigned off = (((unsigned)pk[u] & 0x1FFFFu) << 7) + glb;
            off = (e + u < deg) ? off : glb;
            v[u] = *reinterpret_cast<const uint2*>(
                reinterpret_cast<const char*>(hb) + off);
        }
#pragma unroll
        for (int u = 0; u < 8; ++u) {
            const f32x2v ha = {__uint_as_float(v[u].x << 16),
                               __uint_as_float(v[u].x & 0xFFFF0000u)};
            const f32x2v hc = {__uint_as_float(v[u].y << 16),
                               __uint_as_float(v[u].y & 0xFFFF0000u)};
            const bool sg = (pk[u] >> 20) & 1;
            const f32x2v wa = sg ? hs1a : hs0a;
            const f32x2v wb = sg ? hs1b : hs0b;
            const f32x2v p = wa * ha + wb * hc;
            float sc = p.x + p.y;          // score * log2(e)
            sc += qperm<0xB1>(sc);
            sc += qperm<0x4E>(sc);
            const float ex = (e + u < deg) ? exp2f(sc) : 0.f;
            den += ex;
            ma += ex * ha;
            mb += ex * hc;
        }
    }
    {
        const float inv = 1.0f / (den + 1e-16f);
        float* rowp = bufA + sub * 68 + (gl << 2);
        rowp[0] = ma.x * inv; rowp[1] = ma.y * inv;
        rowp[2] = mb.x * inv; rowp[3] = mb.y * inv;
    }
    __syncthreads();

    // ---------------- tail phase (column tile t = w) ----------------
    const int lr = lane & 15, lk = (lane >> 4) * 8, lrow4 = (lane >> 4) * 4;
    short8 f1h[2], f1l[2], f2h[2], f2l[2], f3h[2], f3l[2];
#pragma unroll
    for (int s = 0; s < 2; ++s) {
        f1h[s] = wf[(((1 * 4 + w) * 2 + s) * 2 + 0) * 64 + lane];
        f1l[s] = wf[(((1 * 4 + w) * 2 + s) * 2 + 1) * 64 + lane];
        f2h[s] = wf[(((2 * 4 + w) * 2 + s) * 2 + 0) * 64 + lane];
        f2l[s] = wf[(((2 * 4 + w) * 2 + s) * 2 + 1) * 64 + lane];
        f3h[s] = wf[(((3 * 4 + w) * 2 + s) * 2 + 0) * 64 + lane];
        f3l[s] = wf[(((3 * 4 + w) * 2 + s) * 2 + 1) * 64 + lane];
    }
    const float bhv = bh[lr + 16 * w];
    const float b1v = b1[lr + 16 * w];
    const float b2v = b2[lr + 16 * w];
    const float escale = 1.0f + eps[0];

    float vh[4];
#pragma unroll
    for (int rg = 0; rg < 4; ++rg)
        vh[rg] = h[(size_t)min(rbase + lrow4 + rg, N - 1) * DIM + lr + 16 * w];

    // stage 1: aggr(bufA) @ Wh^T + bh + escale*h  -> z (bufB)
    short8 ah[2], al[2];
#pragma unroll
    for (int s = 0; s < 2; ++s) {
        float f[8];
#pragma unroll
        for (int e = 0; e < 8; ++e) f[e] = bufA[lr * 68 + 32 * s + lk + e];
        cvt8(f, ah[s], al[s]);
    }
    f32x4 acc = (f32x4){bhv, bhv, bhv, bhv};
#pragma unroll
    for (int s = 0; s < 2; ++s) {
        acc = MFMA16(ah[s], f1h[s], acc);
        acc = MFMA16(ah[s], f1l[s], acc);
        acc = MFMA16(al[s], f1h[s], acc);
    }
#pragma unroll
    for (int rg = 0; rg < 4; ++rg)
        bufB[(lrow4 + rg) * 68 + lr + 16 * w] = fmaf(escale, vh[rg], acc[rg]);
    __syncthreads();

    // stage 2: z(bufB) @ W1^T + b1, relu -> hid (bufA)
#pragma unroll
    for (int s = 0; s < 2; ++s) {
        float f[8];
#pragma unroll
        for (int e = 0; e < 8; ++e) f[e] = bufB[lr * 68 + 32 * s + lk + e];
        cvt8(f, ah[s], al[s]);
    }
    acc = (f32x4){b1v, b1v, b1v, b1v};
#pragma unroll
    for (int s = 0; s < 2; ++s) {
        acc = MFMA16(ah[s], f2h[s], acc);
        acc = MFMA16(ah[s], f2l[s], acc);
        acc = MFMA16(al[s], f2h[s], acc);
    }
#pragma unroll
    for (int rg = 0; rg < 4; ++rg)
        bufA[(lrow4 + rg) * 68 + lr + 16 * w] = fmaxf(acc[rg], 0.f);
    __syncthreads();

    // stage 3: hid(bufA) @ W2^T + b2 -> out
#pragma unroll
    for (int s = 0; s < 2; ++s) {
        float f[8];
#pragma unroll
        for (int e = 0; e < 8; ++e) f[e] = bufA[lr * 68 + 32 * s + lk + e];
        cvt8(f, ah[s], al[s]);
    }
    acc = (f32x4){b2v, b2v, b2v, b2v};
#pragma unroll
    for (int s = 0; s < 2; ++s) {
        acc = MFMA16(ah[s], f3h[s], acc);
        acc = MFMA16(ah[s], f3l[s], acc);
        acc = MFMA16(al[s], f3h[s], acc);
    }
#pragma unroll
    for (int rg = 0; rg < 4; ++rg) {
        const int row = rbase + lrow4 + rg;
        if (row < N) out[(size_t)row * DIM + lr + 16 * w] = acc[rg];
    }
}

extern "C" void kernel_launch(void* const* d_in, const int* in_sizes, int n_in,
                              void* d_out, int out_size, void* d_ws, size_t ws_size,
                              hipStream_t stream) {
    const float* x        = (const float*)d_in[0];
    const int*   ei       = (const int*)d_in[1];
    const int*   esign    = (const int*)d_in[2];
    const float* Wl_w     = (const float*)d_in[3];
    const float* Wl_b     = (const float*)d_in[4];
    const float* sign_tab = (const float*)d_in[5];
    const float* Wh_w     = (const float*)d_in[6];
    const float* Wh_b     = (const float*)d_in[7];
    const float* w1       = (const float*)d_in[8];
    const float* b1       = (const float*)d_in[9];
    const float* w2       = (const float*)d_in[10];
    const float* b2       = (const float*)d_in[11];
    const float* eps      = (const float*)d_in[12];
    float* out = (float*)d_out;

    const int N = in_sizes[0] / DIM;
    const int E = in_sizes[2];
    const int NB = (E + CHUNK - 1) / CHUNK;

    float* h            = (float*)d_ws;                           // 25.6 MB
    unsigned short* hb  = (unsigned short*)(h + (size_t)N * DIM); // 12.8 MB
    int*   records      = (int*)(hb + (size_t)N * DIM);           // NB*CHUNK ints
    int*   edata        = records + (size_t)NB * CHUNK;
    int*   bcursor      = edata + (E + 520);
    int*   offsets      = bcursor + NBUCK;                        // N+1 ints
    short8* wf          = (short8*)(offsets + ((N + 1 + 3) & ~3));// 64 KB
    unsigned int* cnts  = (unsigned int*)(wf + 4096);             // NB*256 uints

    // frag prep + bcursor zero + edata sentinels + offsets[N]
    prep_kernel<<<1, 256, 0, stream>>>(Wl_w, Wh_w, w1, w2, wf, bcursor,
                                       edata, offsets, N, E);

    // fused: h-projection GEMM (odd blocks) || in-LDS-sorted binning (even)
    gemmbin_kernel<<<2 * NB, 256, 0, stream>>>(x, wf, Wl_b, h, hb, N,
                                               ei, esign, bcursor, records,
                                               cnts, E, NB);

    // per-bucket CSR finalize (gather dense runs + node sort)
    build_kernel<<<NBUCK, 256, 0, stream>>>(records, cnts, bcursor,
                                            offsets, edata, N, NB);

    // fused attention + MFMA tail (one 16-row strip per block)
    attntail_kernel<<<(N + 15) / 16, 256, 0, stream>>>(
        h, hb, offsets, edata, sign_tab, wf, Wh_b, b1, b2, eps, out, N);
}

// Round 20
// 108.124 us; speedup vs baseline: 1.0207x; 1.0207x over previous
//
#include <hip/hip_runtime.h>

#define DIM 64
#define NBUCK 256
#define BSHIFT 9
#define BCAP 12288
#define CHUNK 4096

typedef __attribute__((ext_vector_type(4))) float f32x4;
typedef __attribute__((ext_vector_type(2))) float f32x2v;
typedef __attribute__((ext_vector_type(8))) short short8;

#define MFMA16(a, b, c) __builtin_amdgcn_mfma_f32_16x16x32_bf16(a, b, c, 0, 0, 0)

template <int CTRL>
__device__ __forceinline__ float qperm(float v) {
    return __int_as_float(__builtin_amdgcn_update_dpp(
        0, __float_as_int(v), CTRL, 0xF, 0xF, true));
}

// split fp32 -> bf16 hi + bf16 lo (truncation; dropped term ~2^-16 rel)
__device__ __forceinline__ void cvt8(const float* f, short8& hi, short8& lo) {
#pragma unroll
    for (int e = 0; e < 8; ++e) {
        const unsigned u = __float_as_uint(f[e]);
        hi[e] = (short)(u >> 16);
        const float hf = __uint_as_float(u & 0xFFFF0000u);
        lo[e] = (short)(__float_as_uint(f[e] - hf) >> 16);
    }
}

__device__ __forceinline__ unsigned short bf16rne(float f) {
    const unsigned u = __float_as_uint(f);
    return (unsigned short)((u + 0x7FFFu + ((u >> 16) & 1u)) >> 16);
}

// Weight fragments; zero bcursor; edata sentinels; offsets[N]=E.
__global__ __launch_bounds__(256) void prep_kernel(
    const float* __restrict__ Wl, const float* __restrict__ Wh,
    const float* __restrict__ W1, const float* __restrict__ W2,
    short8* __restrict__ wf, int* __restrict__ bcursor,
    int* __restrict__ edata, int* __restrict__ offsets, int N, int E)
{
    const int tid = threadIdx.x;
    bcursor[tid] = 0;
    edata[E + tid] = 0;
    edata[E + 256 + tid] = 0;
    if (tid == 0) offsets[N] = E;
    const int m = tid >> 6, l = tid & 63;
    const float* W = (m == 0) ? Wl : (m == 1) ? Wh : (m == 2) ? W1 : W2;
    const int o = l & 15;
    const int kg = (l >> 4) * 8;
#pragma unroll
    for (int t = 0; t < 4; ++t)
#pragma unroll
        for (int s = 0; s < 2; ++s) {
            float f[8];
#pragma unroll
            for (int e = 0; e < 8; ++e)
                f[e] = W[(o + 16 * t) * DIM + 32 * s + kg + e];
            short8 hi, lo;
            cvt8(f, hi, lo);
            const int base = (((m * 4 + t) * 2 + s) * 2);
            wf[(base + 0) * 64 + l] = hi;
            wf[(base + 1) * 64 + l] = lo;
        }
}

__device__ __forceinline__ int wave_incl_scan(int v, int lane) {
#pragma unroll
    for (int off = 1; off < 64; off <<= 1) {
        int t = __shfl_up(v, (unsigned)off, 64);
        if (lane >= off) v += t;
    }
    return v;
}

// Fused: odd blocks = h-projection GEMM (MFMA); even blocks = edge binning.
// Bin counting-sorts its chunk IN LDS, then streams records out coalesced.
__global__ __launch_bounds__(256, 3) void gemmbin_kernel(
    const float* __restrict__ x, const short8* __restrict__ wf,
    const float* __restrict__ bias, float* __restrict__ h,
    unsigned short* __restrict__ hb, int N,
    const int* __restrict__ ei, const int* __restrict__ sgn,
    int* __restrict__ bcursor, int* __restrict__ records,
    unsigned int* __restrict__ cnts, int E, int NB)
{
    if (blockIdx.x & 1) {
        // ---------------- GEMM path ----------------
        const int l = threadIdx.x & 63;
        const int gw = (blockIdx.x >> 1) * 4 + (threadIdx.x >> 6);
        const int nw = NB * 4;
        const int nstrips = (N + 15) >> 4;
        const int lr = l & 15, lk = (l >> 4) * 8, lrow4 = (l >> 4) * 4;

        short8 wh_[4][2], wl_[4][2];
#pragma unroll
        for (int t = 0; t < 4; ++t)
#pragma unroll
            for (int s = 0; s < 2; ++s) {
                wh_[t][s] = wf[(((0 * 4 + t) * 2 + s) * 2 + 0) * 64 + l];
                wl_[t][s] = wf[(((0 * 4 + t) * 2 + s) * 2 + 1) * 64 + l];
            }
        float b4[4];
#pragma unroll
        for (int t = 0; t < 4; ++t) b4[t] = bias[lr + 16 * t];

        for (int strip = gw; strip < nstrips; strip += nw) {
            const int rbase = strip * 16;
            const int arow = min(rbase + lr, N - 1);
            short8 ah[2], al[2];
#pragma unroll
            for (int s = 0; s < 2; ++s) {
                const float4 p0 = *reinterpret_cast<const float4*>(x + (size_t)arow * DIM + 32 * s + lk);
                const float4 p1 = *reinterpret_cast<const float4*>(x + (size_t)arow * DIM + 32 * s + lk + 4);
                float f[8] = {p0.x, p0.y, p0.z, p0.w, p1.x, p1.y, p1.z, p1.w};
                cvt8(f, ah[s], al[s]);
            }
            f32x4 acc[4];
#pragma unroll
            for (int t = 0; t < 4; ++t) acc[t] = (f32x4){b4[t], b4[t], b4[t], b4[t]};
#pragma unroll
            for (int s = 0; s < 2; ++s) {
#pragma unroll
                for (int t = 0; t < 4; ++t) acc[t] = MFMA16(ah[s], wh_[t][s], acc[t]);
#pragma unroll
                for (int t = 0; t < 4; ++t) acc[t] = MFMA16(ah[s], wl_[t][s], acc[t]);
#pragma unroll
                for (int t = 0; t < 4; ++t) acc[t] = MFMA16(al[s], wh_[t][s], acc[t]);
            }
#pragma unroll
            for (int t = 0; t < 4; ++t)
#pragma unroll
                for (int rg = 0; rg < 4; ++rg) {
                    const int row = rbase + lrow4 + rg;
                    if (row < N) {
                        h[(size_t)row * DIM + lr + 16 * t] = acc[t][rg];
                        hb[(size_t)row * DIM + lr + 16 * t] = bf16rne(acc[t][rg]);
                    }
                }
        }
    } else {
        // ---------------- bin path: in-LDS counting sort ----------------
        const int tid = threadIdx.x;
        const int lane = tid & 63, w = tid >> 6;
        const int blk = blockIdx.x >> 1;
        const int base = blk * CHUNK;
        __shared__ int lcnt[NBUCK];
        __shared__ int lpre[NBUCK];
        __shared__ int wtot_s[4];
        __shared__ int stag[CHUNK];
        lcnt[tid] = 0;
        __syncthreads();
        const int lim = min(CHUNK, E - base);
        if (lim == CHUNK && (E & 3) == 0) {
            int r[16];
#pragma unroll
            for (int j = 0; j < 4; ++j) {
                const int4 a = *(reinterpret_cast<const int4*>(ei + base) + tid * 4 + j);
                r[4*j+0]=a.x; r[4*j+1]=a.y; r[4*j+2]=a.z; r[4*j+3]=a.w;
            }
#pragma unroll
            for (int i = 0; i < 16; ++i) atomicAdd(&lcnt[r[i] >> BSHIFT], 1);
            __syncthreads();
            {
                const int v = lcnt[tid];
                const int inc = wave_incl_scan(v, lane);
                if (lane == 63) wtot_s[w] = inc;
                __syncthreads();
                int add = 0;
#pragma unroll
                for (int i = 0; i < 4; ++i)
                    if (i < w) add += wtot_s[i];
                const int pre = add + inc - v;
                lpre[tid] = pre;
                cnts[blk * NBUCK + tid] = (unsigned)pre | ((unsigned)v << 16);
                if (v) atomicAdd(&bcursor[tid], v);
            }
            __syncthreads();
            lcnt[tid] = 0;
            __syncthreads();
            int cc[16], ss[16];
#pragma unroll
            for (int j = 0; j < 4; ++j) {
                const int4 a = *(reinterpret_cast<const int4*>(ei + E + base) + tid * 4 + j);
                cc[4*j+0]=a.x; cc[4*j+1]=a.y; cc[4*j+2]=a.z; cc[4*j+3]=a.w;
                const int4 s2 = *(reinterpret_cast<const int4*>(sgn + base) + tid * 4 + j);
                ss[4*j+0]=s2.x; ss[4*j+1]=s2.y; ss[4*j+2]=s2.z; ss[4*j+3]=s2.w;
            }
#pragma unroll
            for (int i = 0; i < 16; ++i) {
                const int bkt = r[i] >> BSHIFT;
                const int idx = lpre[bkt] + atomicAdd(&lcnt[bkt], 1);
                stag[idx] = cc[i] | (ss[i] << 17) | ((r[i] & 511) << 18);
            }
            __syncthreads();
            for (int i = tid * 4; i < CHUNK; i += 1024)
                *reinterpret_cast<int4*>(records + base + i) =
                    *reinterpret_cast<const int4*>(stag + i);
        } else {
            for (int k = tid; k < lim; k += 256)
                atomicAdd(&lcnt[ei[base + k] >> BSHIFT], 1);
            __syncthreads();
            {
                const int v = lcnt[tid];
                const int inc = wave_incl_scan(v, lane);
                if (lane == 63) wtot_s[w] = inc;
                __syncthreads();
                int add = 0;
#pragma unroll
                for (int i = 0; i < 4; ++i)
                    if (i < w) add += wtot_s[i];
                const int pre = add + inc - v;
                lpre[tid] = pre;
                cnts[blk * NBUCK + tid] = (unsigned)pre | ((unsigned)v << 16);
                if (v) atomicAdd(&bcursor[tid], v);
            }
            __syncthreads();
            lcnt[tid] = 0;
            __syncthreads();
            for (int k = tid; k < lim; k += 256) {
                const int e = base + k;
                const int rr = ei[e];
                const int cc2 = ei[E + e];
                const int s = sgn[e];
                const int b = rr >> BSHIFT;
                const int idx = lpre[b] + atomicAdd(&lcnt[b], 1);
                stag[idx] = cc2 | (s << 17) | ((rr & 511) << 18);
            }
            __syncthreads();
            for (int i = tid; i < lim; i += 256)
                records[base + i] = stag[i];
        }
    }
}

// One WG per bucket: gather dense per-block runs -> stag, node-sort, emit CSR.
__global__ __launch_bounds__(256) void build_kernel(
    const int* __restrict__ records, const unsigned int* __restrict__ cnts,
    const int* __restrict__ bcursor,
    int* __restrict__ offsets, int* __restrict__ edata, int N, int NB)
{
    const int b = blockIdx.x;
    const int tid = threadIdx.x, lane = tid & 63, w = tid >> 6;
    const int nbase = b << BSHIFT;
    const int nn = min(512, N - nbase);
    if (nn <= 0) return;

    __shared__ int stag[BCAP];
    __shared__ int ncnt[512];
    __shared__ int wtot[8];
    __shared__ int csrb_l[NBUCK];
    __shared__ int blkoff[512];

    {
        const int bv = min(bcursor[tid], BCAP);
        const int inc = wave_incl_scan(bv, lane);
        if (lane == 63) wtot[w] = inc;
        __syncthreads();
        int add = 0;
#pragma unroll
        for (int i = 0; i < 4; ++i)
            if (i < w) add += wtot[i];
        csrb_l[tid] = add + inc - bv;
        __syncthreads();
    }
    const int base_csr = csrb_l[b];
    const int cntb = min(bcursor[b], BCAP);

    const unsigned pc0 = (tid < NB) ? cnts[tid * NBUCK + b] : 0u;
    const unsigned pc1 = (256 + tid < NB) ? cnts[(256 + tid) * NBUCK + b] : 0u;
    const int c0 = (int)(pc0 >> 16), c1 = (int)(pc1 >> 16);
    __syncthreads();
    {
        const int i0 = wave_incl_scan(c0, lane);
        if (lane == 63) wtot[w] = i0;
        const int i1 = wave_incl_scan(c1, lane);
        if (lane == 63) wtot[4 + w] = i1;
        __syncthreads();
        int a0 = 0, a1 = 0;
#pragma unroll
        for (int i = 0; i < 4; ++i) {
            if (i < w) { a0 += wtot[i]; a1 += wtot[4 + i]; }
        }
        const int half = wtot[0] + wtot[1] + wtot[2] + wtot[3];
        blkoff[tid] = a0 + i0 - c0;
        blkoff[256 + tid] = half + a1 + i1 - c1;
    }
    __syncthreads();

    if (tid < NB) {
        const int* src = records + tid * CHUNK + (int)(pc0 & 0xFFFFu);
        const int dst = blkoff[tid];
        for (int i = 0; i < c0; ++i) stag[dst + i] = src[i];
    }
    if (256 + tid < NB) {
        const int* src = records + (256 + tid) * CHUNK + (int)(pc1 & 0xFFFFu);
        const int dst = blkoff[256 + tid];
        for (int i = 0; i < c1; ++i) stag[dst + i] = src[i];
    }
    __syncthreads();

    ncnt[tid] = 0; ncnt[256 + tid] = 0;
    __syncthreads();
    for (int i = tid; i < cntb; i += 256)
        atomicAdd(&ncnt[stag[i] >> 18], 1);
    __syncthreads();
    const int v0 = ncnt[tid], v1 = ncnt[256 + tid];
    const int i0 = wave_incl_scan(v0, lane);
    if (lane == 63) wtot[w] = i0;
    const int i1 = wave_incl_scan(v1, lane);
    if (lane == 63) wtot[4 + w] = i1;
    __syncthreads();
    int a0 = 0, a1 = 0;
#pragma unroll
    for (int i = 0; i < 4; ++i) {
        if (i < w) { a0 += wtot[i]; a1 += wtot[4 + i]; }
    }
    const int half = wtot[0] + wtot[1] + wtot[2] + wtot[3];
    const int e0 = a0 + i0 - v0;
    const int e1 = half + a1 + i1 - v1;
    if (tid < nn)       offsets[nbase + tid]       = base_csr + e0;
    if (256 + tid < nn) offsets[nbase + 256 + tid] = base_csr + e1;
    __syncthreads();
    ncnt[tid] = e0; ncnt[256 + tid] = e1;
    __syncthreads();
    for (int i = tid; i < cntb; i += 256) {
        const int rcd = stag[i];
        const int p = atomicAdd(&ncnt[rcd >> 18], 1);
        edata[base_csr + p] = (rcd & 0x1FFFF) | (((rcd >> 17) & 1) << 20);
    }
}

// Fused attention + tail. Block = one 16-row strip (16 nodes, 4 waves).
// Degree-balanced wave assignment; raw v_exp_f32 (exp2 of pre-scaled score).
__global__ __launch_bounds__(256) void attntail_kernel(
    const float* __restrict__ h, const unsigned short* __restrict__ hb,
    const int* __restrict__ offsets, const int* __restrict__ edata,
    const float* __restrict__ sign_tab, const short8* __restrict__ wf,
    const float* __restrict__ bh, const float* __restrict__ b1,
    const float* __restrict__ b2, const float* __restrict__ eps,
    float* __restrict__ out, int N)
{
    __shared__ float bufA[16 * 68];
    __shared__ float bufB[16 * 68];
    __shared__ int degs[16];
    __shared__ int perm[16];

    const int lane = threadIdx.x & 63;
    const int w    = threadIdx.x >> 6;      // wave id = column tile
    const int gl   = lane & 15;
    const int g    = lane >> 4;
    const int rbase = blockIdx.x * 16;

    // rank-sort the strip's 16 nodes by degree
    if (threadIdx.x < 16) {
        const int nd = rbase + threadIdx.x;
        degs[threadIdx.x] = (nd < N) ? (offsets[nd + 1] - offsets[nd]) : 0;
    }
    __syncthreads();
    if (threadIdx.x < 16) {
        const int d = degs[threadIdx.x];
        int rank = 0;
#pragma unroll
        for (int j = 0; j < 16; ++j) {
            const int dj = degs[j];
            rank += (dj < d) || (dj == d && j < threadIdx.x);
        }
        perm[rank] = threadIdx.x;
    }
    __syncthreads();

    const int sub  = perm[(w << 2) + g];     // strip-row this group handles
    const int node = rbase + sub;
    const bool alive = node < N;
    const int nidx = alive ? node : 0;

    // ---------------- attention phase ----------------
    const int beg = offsets[nidx];
    const int deg = alive ? (offsets[nidx + 1] - beg) : 0;

    const float4 hi = *reinterpret_cast<const float4*>(h + ((unsigned)nidx << 6) + (gl << 2));
    const float L2E = 1.44269504f;
    const float4 hiL = make_float4(hi.x * L2E, hi.y * L2E, hi.z * L2E, hi.w * L2E);
    const float4 s0 = *reinterpret_cast<const float4*>(sign_tab + ((gl & 3) << 2));
    const float4 s1 = *reinterpret_cast<const float4*>(sign_tab + 16 + ((gl & 3) << 2));
    const f32x2v hs0a = {hiL.x * s0.x, hiL.y * s0.y};
    const f32x2v hs0b = {hiL.z * s0.z, hiL.w * s0.w};
    const f32x2v hs1a = {hiL.x * s1.x, hiL.y * s1.y};
    const f32x2v hs1b = {hiL.z * s1.z, hiL.w * s1.w};

    int maxdeg = max(deg, __shfl_xor(deg, 16, 64));
    maxdeg = max(maxdeg, __shfl_xor(maxdeg, 32, 64));

    float den = 0.f;
    f32x2v ma = {0.f, 0.f}, mb = {0.f, 0.f};
    const unsigned glb = (unsigned)(gl << 3);

    for (int e = 0; e < maxdeg; e += 8) {
        int pk[8];
#pragma unroll
        for (int u = 0; u < 8; ++u)
            pk[u] = edata[(unsigned)(beg + e + u)];
        uint2 v[8];
#pragma unroll
        for (int u = 0; u < 8; ++u) {
            unsigned off = (((unsigned)pk[u] & 0x1FFFFu) << 7) + glb;
            off = (e + u < deg) ? off : glb;
            v[u] = *reinterpret_cast<const uint2*>(
                reinterpret_cast<const char*>(hb) + off);
        }
#pragma unroll
        for (int u = 0; u < 8; ++u) {
            const f32x2v ha = {__uint_as_float(v[u].x << 16),
                               __uint_as_float(v[u].x & 0xFFFF0000u)};
            const f32x2v hc = {__uint_as_float(v[u].y << 16),
                               __uint_as_float(v[u].y & 0xFFFF0000u)};
            const bool sg = (pk[u] >> 20) & 1;
            const f32x2v wa = sg ? hs1a : hs0a;
            const f32x2v wb = sg ? hs1b : hs0b;
            const f32x2v p = wa * ha + wb * hc;
            float sc = p.x + p.y;          // score * log2(e)
            sc += qperm<0xB1>(sc);
            sc += qperm<0x4E>(sc);
            // raw v_exp_f32 (2^x), no libm range handling (r18 regression fix)
            float ex = __builtin_amdgcn_exp2f(sc);
            ex = (e + u < deg) ? ex : 0.f;
            den += ex;
            ma += ex * ha;
            mb += ex * hc;
        }
    }
    {
        const float inv = 1.0f / (den + 1e-16f);
        float* rowp = bufA + sub * 68 + (gl << 2);
        rowp[0] = ma.x * inv; rowp[1] = ma.y * inv;
        rowp[2] = mb.x * inv; rowp[3] = mb.y * inv;
    }
    __syncthreads();

    // ---------------- tail phase (column tile t = w) ----------------
    const int lr = lane & 15, lk = (lane >> 4) * 8, lrow4 = (lane >> 4) * 4;
    short8 f1h[2], f1l[2], f2h[2], f2l[2], f3h[2], f3l[2];
#pragma unroll
    for (int s = 0; s < 2; ++s) {
        f1h[s] = wf[(((1 * 4 + w) * 2 + s) * 2 + 0) * 64 + lane];
        f1l[s] = wf[(((1 * 4 + w) * 2 + s) * 2 + 1) * 64 + lane];
        f2h[s] = wf[(((2 * 4 + w) * 2 + s) * 2 + 0) * 64 + lane];
        f2l[s] = wf[(((2 * 4 + w) * 2 + s) * 2 + 1) * 64 + lane];
        f3h[s] = wf[(((3 * 4 + w) * 2 + s) * 2 + 0) * 64 + lane];
        f3l[s] = wf[(((3 * 4 + w) * 2 + s) * 2 + 1) * 64 + lane];
    }
    const float bhv = bh[lr + 16 * w];
    const float b1v = b1[lr + 16 * w];
    const float b2v = b2[lr + 16 * w];
    const float escale = 1.0f + eps[0];

    float vh[4];
#pragma unroll
    for (int rg = 0; rg < 4; ++rg)
        vh[rg] = h[(size_t)min(rbase + lrow4 + rg, N - 1) * DIM + lr + 16 * w];

    // stage 1: aggr(bufA) @ Wh^T + bh + escale*h  -> z (bufB)
    short8 ah[2], al[2];
#pragma unroll
    for (int s = 0; s < 2; ++s) {
        float f[8];
#pragma unroll
        for (int e = 0; e < 8; ++e) f[e] = bufA[lr * 68 + 32 * s + lk + e];
        cvt8(f, ah[s], al[s]);
    }
    f32x4 acc = (f32x4){bhv, bhv, bhv, bhv};
#pragma unroll
    for (int s = 0; s < 2; ++s) {
        acc = MFMA16(ah[s], f1h[s], acc);
        acc = MFMA16(ah[s], f1l[s], acc);
        acc = MFMA16(al[s], f1h[s], acc);
    }
#pragma unroll
    for (int rg = 0; rg < 4; ++rg)
        bufB[(lrow4 + rg) * 68 + lr + 16 * w] = fmaf(escale, vh[rg], acc[rg]);
    __syncthreads();

    // stage 2: z(bufB) @ W1^T + b1, relu -> hid (bufA)
#pragma unroll
    for (int s = 0; s < 2; ++s) {
        float f[8];
#pragma unroll
        for (int e = 0; e < 8; ++e) f[e] = bufB[lr * 68 + 32 * s + lk + e];
        cvt8(f, ah[s], al[s]);
    }
    acc = (f32x4){b1v, b1v, b1v, b1v};
#pragma unroll
    for (int s = 0; s < 2; ++s) {
        acc = MFMA16(ah[s], f2h[s], acc);
        acc = MFMA16(ah[s], f2l[s], acc);
        acc = MFMA16(al[s], f2h[s], acc);
    }
#pragma unroll
    for (int rg = 0; rg < 4; ++rg)
        bufA[(lrow4 + rg) * 68 + lr + 16 * w] = fmaxf(acc[rg], 0.f);
    __syncthreads();

    // stage 3: hid(bufA) @ W2^T + b2 -> out
#pragma unroll
    for (int s = 0; s < 2; ++s) {
        float f[8];
#pragma unroll
        for (int e = 0; e < 8; ++e) f[e] = bufA[lr * 68 + 32 * s + lk + e];
        cvt8(f, ah[s], al[s]);
    }
    acc = (f32x4){b2v, b2v, b2v, b2v};
#pragma unroll
    for (int s = 0; s < 2; ++s) {
        acc = MFMA16(ah[s], f3h[s], acc);
        acc = MFMA16(ah[s], f3l[s], acc);
        acc = MFMA16(al[s], f3h[s], acc);
    }
#pragma unroll
    for (int rg = 0; rg < 4; ++rg) {
        const int row = rbase + lrow4 + rg;
        if (row < N) out[(size_t)row * DIM + lr + 16 * w] = acc[rg];
    }
}

extern "C" void kernel_launch(void* const* d_in, const int* in_sizes, int n_in,
                              void* d_out, int out_size, void* d_ws, size_t ws_size,
                              hipStream_t stream) {
    const float* x        = (const float*)d_in[0];
    const int*   ei       = (const int*)d_in[1];
    const int*   esign    = (const int*)d_in[2];
    const float* Wl_w     = (const float*)d_in[3];
    const float* Wl_b     = (const float*)d_in[4];
    const float* sign_tab = (const float*)d_in[5];
    const float* Wh_w     = (const float*)d_in[6];
    const float* Wh_b     = (const float*)d_in[7];
    const float* w1       = (const float*)d_in[8];
    const float* b1       = (const float*)d_in[9];
    const float* w2       = (const float*)d_in[10];
    const float* b2       = (const float*)d_in[11];
    const float* eps      = (const float*)d_in[12];
    float* out = (float*)d_out;

    const int N = in_sizes[0] / DIM;
    const int E = in_sizes[2];
    const int NB = (E + CHUNK - 1) / CHUNK;

    float* h            = (float*)d_ws;                           // 25.6 MB
    unsigned short* hb  = (unsigned short*)(h + (size_t)N * DIM); // 12.8 MB
    int*   records      = (int*)(hb + (size_t)N * DIM);           // NB*CHUNK ints
    int*   edata        = records + (size_t)NB * CHUNK;
    int*   bcursor      = edata + (E + 520);
    int*   offsets      = bcursor + NBUCK;                        // N+1 ints
    short8* wf          = (short8*)(offsets + ((N + 1 + 3) & ~3));// 64 KB
    unsigned int* cnts  = (unsigned int*)(wf + 4096);             // NB*256 uints

    // frag prep + bcursor zero + edata sentinels + offsets[N]
    prep_kernel<<<1, 256, 0, stream>>>(Wl_w, Wh_w, w1, w2, wf, bcursor,
                                       edata, offsets, N, E);

    // fused: h-projection GEMM (odd blocks) || in-LDS-sorted binning (even)
    gemmbin_kernel<<<2 * NB, 256, 0, stream>>>(x, wf, Wl_b, h, hb, N,
                                               ei, esign, bcursor, records,
                                               cnts, E, NB);

    // per-bucket CSR finalize (gather dense runs + node sort)
    build_kernel<<<NBUCK, 256, 0, stream>>>(records, cnts, bcursor,
                                            offsets, edata, N, NB);

    // fused attention + MFMA tail (one 16-row strip per block)
    attntail_kernel<<<(N + 15) / 16, 256, 0, stream>>>(
        h, hb, offsets, edata, sign_tab, wf, Wh_b, b1, b2, eps, out, N);
}